// Round 12
// baseline (565.620 us; speedup 1.0000x reference)
//
#include <hip/hip_runtime.h>
#include <hip/hip_bf16.h>
#include <math.h>

#define IGNORE_INDEX (-100)

constexpr int BT = 2048, H = 4096, V = 32000;
constexpr int BM = 256, BN = 256, BK = 64;
constexpr int KT = H / BK;            // 64 k-tiles
constexpr int MT2 = BT / BM;          // 8
constexpr int NT2 = V / BN;           // 125
constexpr int NCHUNK = NT2 * 4;       // 500 partial chunks/row (64 cols each)

typedef int   i32x4  __attribute__((ext_vector_type(4)));
typedef int   i32x8  __attribute__((ext_vector_type(8)));
typedef float f32x16 __attribute__((ext_vector_type(16)));

// e8m0 scale byte for 2^-7 (operands are pre-scaled by 2^7 at conversion)
#define SC8 120

__device__ __forceinline__ void gload_lds16(const char* g, char* l) {
  __builtin_amdgcn_global_load_lds(
      (const __attribute__((address_space(1))) unsigned int*)(g),
      (__attribute__((address_space(3))) unsigned int*)(l), 16, 0, 0);
}

#define BAR()        asm volatile("s_barrier" ::: "memory")
#define WAIT_VM(N)   asm volatile("s_waitcnt vmcnt(" #N ")" ::: "memory")
#define SB0()        __builtin_amdgcn_sched_barrier(0)

// ---------------------------------------------------------------------------
// fp32 -> fp8 e4m3 bulk convert with x128 pre-scale (W: linear (V,H) layout)
// ---------------------------------------------------------------------------
__global__ __launch_bounds__(256)
void convert_fp8(const float* __restrict__ src, char* __restrict__ dst,
                 int n8) {
  int i = blockIdx.x * blockDim.x + threadIdx.x;
  const int stride = gridDim.x * blockDim.x;
  for (; i < n8; i += stride) {
    const float4 f0 = ((const float4*)src)[2 * i];
    const float4 f1 = ((const float4*)src)[2 * i + 1];
    const float S = 128.f;
    int lo = 0, hi = 0;
    lo = __builtin_amdgcn_cvt_pk_fp8_f32(f0.x * S, f0.y * S, lo, false);
    lo = __builtin_amdgcn_cvt_pk_fp8_f32(f0.z * S, f0.w * S, lo, true);
    hi = __builtin_amdgcn_cvt_pk_fp8_f32(f1.x * S, f1.y * S, hi, false);
    hi = __builtin_amdgcn_cvt_pk_fp8_f32(f1.z * S, f1.w * S, hi, true);
    int2 v; v.x = lo; v.y = hi;
    ((int2*)dst)[i] = v;
  }
}

// ---------------------------------------------------------------------------
// X: fp32 -> fp8 into MFMA-fragment-tiled layout:
// Xt[rg = row>>5][kt = k>>6][lane = (row&31) + 32*((k>>5)&1)][k&31]
// so an A-fragment load in the GEMM is base + lane*32 (fully coalesced).
// Matches the r10/r11-VERIFIED A layout (lane l31 = row, h = k-half).
// ---------------------------------------------------------------------------
__global__ __launch_bounds__(256)
void convert_x_fp8_tiled(const float* __restrict__ src,
                         char* __restrict__ dst, int n8) {
  int i = blockIdx.x * blockDim.x + threadIdx.x;
  const int stride = gridDim.x * blockDim.x;
  for (; i < n8; i += stride) {
    const float4 f0 = ((const float4*)src)[2 * i];
    const float4 f1 = ((const float4*)src)[2 * i + 1];
    const float S = 128.f;
    int lo = 0, hi = 0;
    lo = __builtin_amdgcn_cvt_pk_fp8_f32(f0.x * S, f0.y * S, lo, false);
    lo = __builtin_amdgcn_cvt_pk_fp8_f32(f0.z * S, f0.w * S, lo, true);
    hi = __builtin_amdgcn_cvt_pk_fp8_f32(f1.x * S, f1.y * S, hi, false);
    hi = __builtin_amdgcn_cvt_pk_fp8_f32(f1.z * S, f1.w * S, hi, true);
    int2 v; v.x = lo; v.y = hi;
    const int r  = i >> 9;            // row (H/8 = 512 octets per row)
    const int k0 = (i & 511) * 8;     // k-byte offset in row
    const int lane = (r & 31) + ((k0 >> 5) & 1) * 32;
    const size_t addr =
        ((size_t)((r >> 5) * 64 + (k0 >> 6)) * 64 + lane) * 32 + (k0 & 31);
    *(int2*)(dst + addr) = v;
  }
}

// ---------------------------------------------------------------------------
// 256x256 MX-fp8 GEMM, A DIRECT FROM L2 (fragment-tiled Xt, no LDS for A),
// B staged in LDS (r11's verified swizzle/path). 1 barrier per K-tile:
//   [STAGE_B(next); RDB(cur); LOADA(next->alt regs); MFMA x8; SB0; VM(8); BAR]
// Safety: stage(buf^1) issues after BAR(t); buf^1's last ds_reads are pinned
// before BAR(t) (operand lgkm wait precedes MFMA, MFMA pinned by SB0).
// VM(8) leaves only the 8 A-prefetch loads in flight -> B stages land before
// BAR; compiler's counted vmcnt for A operands (>=10) never drains them.
// ---------------------------------------------------------------------------
__global__ __launch_bounds__(512, 2)
void gemm_lse_adirect(const char* __restrict__ Wq,   // (V,H) fp8 linear
                      const char* __restrict__ Xt,   // tiled fp8 (8 MB)
                      const int* __restrict__ target,
                      const float* __restrict__ bias,
                      float* __restrict__ pM, float* __restrict__ pS,
                      float* __restrict__ gold)
{
  __shared__ char Bs[32768];   // [buf:2][256 rows][64 B]

  const int tid  = threadIdx.x;
  const int lane = tid & 63;
  const int wid  = tid >> 6;
  const int wr   = wid >> 2;        // 0..1 : rows [wr*128, +128)
  const int wcol = wid & 3;         // 0..3 : cols [wcol*64, +64)

  // XCD swizzle: nwg = 1000 = 8*125, bijective
  const int bid = (int)blockIdx.x;
  const int swz = (bid & 7) * 125 + (bid >> 3);
  const int mt = swz & (MT2 - 1);
  const int nt = swz >> 3;
  const int m0 = mt * BM, n0 = nt * BN;

  const int l31 = lane & 31;
  const int h   = lane >> 5;
  // B read swizzle (r11-verified): slot(row,q) = q ^ ((row>>1)&3)
  const int r2  = (l31 >> 1) & 3;
  const int s0  = ((2 * h) ^ r2) << 4;
  const int s1  = ((2 * h + 1) ^ r2) << 4;
  const int bbase = (wcol * 64 + l31) * 64;

  // B staging: lane covers row lane>>2, slot lane&3; source pre-swizzled
  const int srow  = lane >> 2;
  const int sslot = ((lane & 3) ^ ((lane >> 3) & 3)) << 4;
  const char* bsrc = Wq + (size_t)(n0 + wid * 32 + srow) * H + sslot;

  // A direct: row-group base for this wave; per-lane byte offset
  const int rg0 = mt * 8 + wr * 4;
  const int aoff = lane * 32;

  f32x16 acc[8] = {};               // [mi*2 + nj]
  i32x8 aC[4], aN[4], bF0, bF1;

#define STAGE_B(BUF, T)                                                       \
  { gload_lds16(bsrc + (T) * BK,                                              \
                &Bs[(BUF) * 16384 + wid * 2048 + lane * 16]);                 \
    gload_lds16(bsrc + (size_t)16 * H + (T) * BK,                             \
                &Bs[(BUF) * 16384 + wid * 2048 + 1024 + lane * 16]); }

#define RDB(DST, BUF, NJ)                                                     \
  { i32x4 lo = *(const i32x4*)&Bs[(BUF) * 16384 + bbase + (NJ) * 2048 + s0];  \
    i32x4 hi = *(const i32x4*)&Bs[(BUF) * 16384 + bbase + (NJ) * 2048 + s1];  \
    DST[0] = lo[0]; DST[1] = lo[1]; DST[2] = lo[2]; DST[3] = lo[3];           \
    DST[4] = hi[0]; DST[5] = hi[1]; DST[6] = hi[2]; DST[7] = hi[3]; }

#define LOADA(DST, T)                                                         \
  { _Pragma("unroll")                                                         \
    for (int mi = 0; mi < 4; ++mi) {                                          \
      const char* ap = Xt + ((size_t)((rg0 + mi) * 64 + (T)) << 11) + aoff;   \
      i32x4 lo = *(const i32x4*)(ap);                                         \
      i32x4 hi = *(const i32x4*)(ap + 16);                                    \
      DST[mi][0]=lo[0]; DST[mi][1]=lo[1]; DST[mi][2]=lo[2]; DST[mi][3]=lo[3]; \
      DST[mi][4]=hi[0]; DST[mi][5]=hi[1]; DST[mi][6]=hi[2]; DST[mi][7]=hi[3]; \
    } }

#define MFMA8(ASET)                                                           \
  { __builtin_amdgcn_s_setprio(1);                                            \
    _Pragma("unroll")                                                         \
    for (int mi = 0; mi < 4; ++mi) {                                          \
      acc[mi*2+0] = __builtin_amdgcn_mfma_scale_f32_32x32x64_f8f6f4(          \
          ASET[mi], bF0, acc[mi*2+0], 0, 0, 0, SC8, 0, SC8);                  \
      acc[mi*2+1] = __builtin_amdgcn_mfma_scale_f32_32x32x64_f8f6f4(          \
          ASET[mi], bF1, acc[mi*2+1], 0, 0, 0, SC8, 0, SC8);                  \
    }                                                                         \
    __builtin_amdgcn_s_setprio(0); }

  // ---- prologue: A(0) -> aC, B(0) -> buf0, full drain, barrier
  LOADA(aC, 0);
  STAGE_B(0, 0);
  WAIT_VM(0);
  BAR();

  // ---- main loop: 2 K-tiles per iteration (even: buf0/aC, odd: buf1/aN)
  for (int t = 0; t < KT - 2; t += 2) {
    // even: tile t (buf0); stage t+1 -> buf1; prefetch A(t+1) -> aN
    STAGE_B(1, t + 1);
    RDB(bF0, 0, 0); RDB(bF1, 0, 1);
    LOADA(aN, t + 1);
    MFMA8(aC);
    SB0(); WAIT_VM(8); BAR();
    // odd: tile t+1 (buf1); stage t+2 -> buf0; prefetch A(t+2) -> aC
    STAGE_B(0, t + 2);
    RDB(bF0, 1, 0); RDB(bF1, 1, 1);
    LOADA(aC, t + 2);
    MFMA8(aN);
    SB0(); WAIT_VM(8); BAR();
  }
  // ---- tail: tile 62 (buf0, stage 63), tile 63 (buf1)
  STAGE_B(1, KT - 1);
  RDB(bF0, 0, 0); RDB(bF1, 0, 1);
  LOADA(aN, KT - 1);
  MFMA8(aC);
  SB0(); WAIT_VM(8); BAR();
  RDB(bF0, 1, 0); RDB(bF1, 1, 1);
  MFMA8(aN);

#undef STAGE_B
#undef RDB
#undef LOADA
#undef MFMA8

  // ---- epilogue (32x32 C/D: col=lane&31, row=(r&3)+8*(r>>2)+4*h) — verified
  const int colbase = n0 + wcol * 64;
  float bv[2];
#pragma unroll
  for (int nj = 0; nj < 2; ++nj) bv[nj] = bias[colbase + nj * 32 + l31];

  const int chunk = nt * 4 + wcol;
#pragma unroll
  for (int mi = 0; mi < 4; ++mi) {
#pragma unroll
    for (int r = 0; r < 16; ++r) {
      const int row = m0 + wr * 128 + mi * 32 + (r & 3) + 8 * (r >> 2) + 4 * h;
      const float v0 = acc[mi * 2 + 0][r] + bv[0];
      const float v1 = acc[mi * 2 + 1][r] + bv[1];
      float mx = fmaxf(v0, v1);
#pragma unroll
      for (int d = 1; d < 32; d <<= 1) mx = fmaxf(mx, __shfl_xor(mx, d));
      float s = expf(v0 - mx) + expf(v1 - mx);
#pragma unroll
      for (int d = 1; d < 32; d <<= 1) s += __shfl_xor(s, d);
      if (l31 == 0) {
        pM[(size_t)row * NCHUNK + chunk] = mx;
        pS[(size_t)row * NCHUNK + chunk] = s;
      }
      const int t = target[row];
      const int d0 = t - colbase;
      if (d0 >= 0 && d0 < 64 && l31 == (d0 & 31)) {
        gold[row] = (d0 >> 5) ? v1 : v0;
      }
    }
  }
}

// one wave per row: combine 500 (max, sumexp) chunks -> rowterm
__global__ __launch_bounds__(256)
void reduce_lse(const float* __restrict__ pM, const float* __restrict__ pS,
                const float* __restrict__ gold, const int* __restrict__ target,
                const float* __restrict__ lw, float* __restrict__ rowterm)
{
  const int wid = threadIdx.x >> 6, lane = threadIdx.x & 63;
  const int row = blockIdx.x * 4 + wid;
  if (row >= BT) return;
  const float* pm = pM + (size_t)row * NCHUNK;
  const float* ps = pS + (size_t)row * NCHUNK;
  float m = -INFINITY;
  for (int c2 = lane; c2 < NCHUNK; c2 += 64) m = fmaxf(m, pm[c2]);
#pragma unroll
  for (int d = 1; d < 64; d <<= 1) m = fmaxf(m, __shfl_xor(m, d));
  float s = 0.f;
  for (int c2 = lane; c2 < NCHUNK; c2 += 64) s += ps[c2] * expf(pm[c2] - m);
#pragma unroll
  for (int d = 1; d < 64; d <<= 1) s += __shfl_xor(s, d);
  if (lane == 0) {
    const int t = target[row];
    float term = 0.f;
    if (t != IGNORE_INDEX) term = (m + logf(s) - gold[row]) * lw[row];
    rowterm[row] = term;
  }
}

// single-block deterministic finalize
__global__ __launch_bounds__(256)
void finalize(const float* __restrict__ rowterm, const int* __restrict__ target,
              const float* __restrict__ rsw, const int* __restrict__ gas,
              float* __restrict__ out)
{
  __shared__ float sred[4];
  __shared__ int cred[4];
  const int tid = threadIdx.x;
  float s = 0.f;
  int cnt = 0;
  for (int i = tid; i < BT; i += 256) {
    s += rowterm[i];
    cnt += (target[i] != IGNORE_INDEX) ? 1 : 0;
  }
#pragma unroll
  for (int d = 1; d < 64; d <<= 1) {
    s += __shfl_xor(s, d);
    cnt += __shfl_xor(cnt, d);
  }
  const int wid = tid >> 6, lane = tid & 63;
  if (lane == 0) { sred[wid] = s; cred[wid] = cnt; }
  __syncthreads();
  if (tid == 0) {
    const float st = sred[0] + sred[1] + sred[2] + sred[3];
    const int ct = cred[0] + cred[1] + cred[2] + cred[3];
    const float n = (float)((ct > 0) ? ct : 1);
    const float rs = rsw[0];
    float loss = (rs == 0.f) ? 0.f : (st / n) / rs;
    loss /= (float)gas[0];
    out[0] = loss;
  }
}

extern "C" void kernel_launch(void* const* d_in, const int* in_sizes, int n_in,
                              void* d_out, int out_size, void* d_ws, size_t ws_size,
                              hipStream_t stream)
{
  const float* Wt     = (const float*)d_in[0];  // lin_weight (V,H)
  const float* X      = (const float*)d_in[1];  // _input (BT,H)
  const int*   target = (const int*)d_in[2];
  const float* bias   = (const float*)d_in[3];
  const float* lw     = (const float*)d_in[4];
  const float* rsw    = (const float*)d_in[5];
  const int*   gas    = (const int*)d_in[6];
  float* out = (float*)d_out;

  const size_t nW = (size_t)V * H, nX = (size_t)BT * H;

  char* Wq = (char*)d_ws;                       // V*H fp8 (linear)
  char* Xt = Wq + nW;                           // BT*H fp8 (fragment-tiled)
  float* pM = (float*)(Xt + nX);
  float* pS = pM + (size_t)BT * NCHUNK;
  float* gold = pS + (size_t)BT * NCHUNK;
  float* rowterm = gold + BT;

  convert_fp8<<<dim3(2048), dim3(256), 0, stream>>>(Wt, Wq, (int)(nW / 8));
  convert_x_fp8_tiled<<<dim3(1024), dim3(256), 0, stream>>>(X, Xt,
                                                            (int)(nX / 8));
  gemm_lse_adirect<<<dim3(MT2 * NT2), dim3(512), 0, stream>>>(Wq, Xt, target,
                                                              bias, pM, pS,
                                                              gold);
  reduce_lse<<<dim3(BT / 4), dim3(256), 0, stream>>>(pM, pS, gold, target, lw,
                                                     rowterm);
  finalize<<<dim3(1), dim3(256), 0, stream>>>(rowterm, target, rsw, gas, out);
}